// Round 2
// baseline (1281.177 us; speedup 1.0000x reference)
//
#include <hip/hip_runtime.h>
#include <hip/hip_bf16.h>

#define BT 2048
#define T_SEQ 1024
#define DIM 1024
#define DINNER 2048
#define DSTATE 128
#define HEADDIM 64
#define NHEADS 32
#define CONVCH 2304
#define DINPROJ 4384
#define EPS_F 1e-5f

typedef __bf16 bf16x8 __attribute__((ext_vector_type(8)));
typedef float f32x4 __attribute__((ext_vector_type(4)));

__device__ __forceinline__ float b2f(unsigned short u) {
  union { unsigned int i; float f; } v; v.i = ((unsigned int)u) << 16; return v.f;
}
__device__ __forceinline__ unsigned short f2b(float f) {
  unsigned int x = __float_as_uint(f);
  return (unsigned short)((x + 0x7fffu + ((x >> 16) & 1u)) >> 16);
}

// ---------------- fp32 -> bf16 weight conversion ----------------
__global__ void cvt_k(const float* __restrict__ in, unsigned short* __restrict__ out, int n) {
  int i = (blockIdx.x * 256 + threadIdx.x) * 4;
  if (i < n) {
    float4 v = *(const float4*)(in + i);
    out[i + 0] = f2b(v.x);
    out[i + 1] = f2b(v.y);
    out[i + 2] = f2b(v.z);
    out[i + 3] = f2b(v.w);
  }
}

// ---------------- embed lookup (fp32 table -> fp32 residual + bf16 copy) ----------------
__global__ void embed_k(const int* __restrict__ x, const float* __restrict__ emb,
                        float* __restrict__ h, unsigned short* __restrict__ hb) {
  int t = blockIdx.x;
  int tok = x[t];
  int d = threadIdx.x;
#pragma unroll
  for (int j = 0; j < 4; ++j, d += 256) {
    float v = emb[(size_t)tok * DIM + d];
    h[(size_t)t * DIM + d] = v;
    hb[(size_t)t * DIM + d] = f2b(v);
  }
}

// ---------------- GEMM: C[M,N] = A[M,K] * Bw[N,K]^T (bf16 in, fp32 acc) ----------------
// MODE 0: Cout=bf16 (stride N), cols >= 4352 also dumped fp32 to aux (dt_raw, stride 32)
// MODE 1: aux (fp32, stride N) += acc (residual); aux2 = bf16(aux)
// MODE 2: aux (fp32, stride N) = acc   (final logits, fp32 out)
template <int MODE>
__global__ void gemm_bt(const unsigned short* __restrict__ A,
                        const unsigned short* __restrict__ Bw,
                        int M, int N, int K,
                        unsigned short* __restrict__ Cout,
                        float* __restrict__ aux,
                        unsigned short* __restrict__ aux2) {
  __shared__ __align__(16) unsigned short As[128 * 32];
  __shared__ __align__(16) unsigned short Bs[128 * 32];
  const int tid = threadIdx.x;
  const int lane = tid & 63;
  const int wave = tid >> 6;
  const int m0 = blockIdx.y * 128;
  const int n0 = blockIdx.x * 128;
  const int wm = (wave >> 1) * 64;
  const int wn = (wave & 1) * 64;
  const int quad = lane >> 4;
  const int r = lane & 15;

  f32x4 acc[4][4];
#pragma unroll
  for (int i = 0; i < 4; ++i)
#pragma unroll
    for (int j = 0; j < 4; ++j) acc[i][j] = f32x4{0.f, 0.f, 0.f, 0.f};

  const int idx0 = tid, idx1 = tid + 256;
  const int ra0 = idx0 >> 2, ca0 = (idx0 & 3) * 8;
  const int ra1 = idx1 >> 2, ca1 = (idx1 & 3) * 8;
  int rb0 = n0 + ra0; if (rb0 >= N) rb0 = N - 1;
  int rb1 = n0 + ra1; if (rb1 >= N) rb1 = N - 1;

  for (int k0 = 0; k0 < K; k0 += 32) {
    uint4 a0 = *(const uint4*)(A + (size_t)(m0 + ra0) * K + k0 + ca0);
    uint4 a1 = *(const uint4*)(A + (size_t)(m0 + ra1) * K + k0 + ca1);
    uint4 b0 = *(const uint4*)(Bw + (size_t)rb0 * K + k0 + ca0);
    uint4 b1 = *(const uint4*)(Bw + (size_t)rb1 * K + k0 + ca1);
    __syncthreads();
    *(uint4*)(As + idx0 * 8) = a0;
    *(uint4*)(As + idx1 * 8) = a1;
    *(uint4*)(Bs + idx0 * 8) = b0;
    *(uint4*)(Bs + idx1 * 8) = b1;
    __syncthreads();
    const bf16x8* ap = (const bf16x8*)As;
    const bf16x8* bp = (const bf16x8*)Bs;
    bf16x8 af[4], bfr[4];
#pragma unroll
    for (int mt = 0; mt < 4; ++mt) af[mt] = ap[(wm + mt * 16 + r) * 4 + quad];
#pragma unroll
    for (int nt = 0; nt < 4; ++nt) bfr[nt] = bp[(wn + nt * 16 + r) * 4 + quad];
#pragma unroll
    for (int mt = 0; mt < 4; ++mt)
#pragma unroll
      for (int nt = 0; nt < 4; ++nt)
        acc[mt][nt] = __builtin_amdgcn_mfma_f32_16x16x32_bf16(af[mt], bfr[nt], acc[mt][nt], 0, 0, 0);
  }

#pragma unroll
  for (int mt = 0; mt < 4; ++mt) {
#pragma unroll
    for (int nt = 0; nt < 4; ++nt) {
#pragma unroll
      for (int i = 0; i < 4; ++i) {
        int gm = m0 + wm + mt * 16 + quad * 4 + i;
        int gn = n0 + wn + nt * 16 + r;
        if (gn < N) {
          float v = acc[mt][nt][i];
          if (MODE == 0) {
            Cout[(size_t)gm * N + gn] = f2b(v);
            if (gn >= DINNER + CONVCH)
              aux[(size_t)gm * NHEADS + (gn - (DINNER + CONVCH))] = v;
          } else if (MODE == 1) {
            size_t o = (size_t)gm * N + gn;
            float hnv = aux[o] + v;
            aux[o] = hnv;
            aux2[o] = f2b(hnv);
          } else {
            aux[(size_t)gm * N + gn] = v;
          }
        }
      }
    }
  }
}

// ---------------- causal conv (K=4) + silu; B/C channels also dumped fp32 ----------------
__global__ void conv_k(const unsigned short* __restrict__ zx,
                       const float* __restrict__ cw,
                       const float* __restrict__ cb,
                       unsigned short* __restrict__ xbc,
                       float* __restrict__ bcf) {
  int t = blockIdx.x;
  int tt = t & (T_SEQ - 1);
  for (int c = threadIdx.x; c < CONVCH; c += 256) {
    float acc = cb[c];
#pragma unroll
    for (int k = 0; k < 4; ++k) {
      int tp = tt - 3 + k;
      if (tp >= 0)
        acc += b2f(zx[(size_t)(t - 3 + k) * DINPROJ + DINNER + c]) * cw[c * 4 + k];
    }
    float s = acc / (1.f + expf(-acc));
    xbc[(size_t)t * CONVCH + c] = f2b(s);
    if (c >= DINNER) bcf[(size_t)t * 256 + (c - DINNER)] = s;
  }
}

// ---------------- dt = softplus(dt_raw + bias); dA = exp(-dt * exp(A_log)) ----------------
__global__ void dt_k(const float* __restrict__ dtraw, const float* __restrict__ dtb,
                     const float* __restrict__ alog,
                     float* __restrict__ dtf, float* __restrict__ dAf) {
  int i = blockIdx.x * 256 + threadIdx.x;
  int h = i & (NHEADS - 1);
  float xx = dtraw[i] + dtb[h];
  float sp = (xx > 20.f) ? xx : log1pf(expf(xx));
  dtf[i] = sp;
  dAf[i] = expf(-sp * expf(alog[h]));
}

// ---------------- sequential selective scan, 1 wave per (b,h,p-octant), no barriers ------
__global__ __launch_bounds__(64) void scan_k(
    const unsigned short* __restrict__ xbc,
    const float* __restrict__ bcf,
    const unsigned short* __restrict__ zx,
    const float* __restrict__ dtf, const float* __restrict__ dAf,
    const float* __restrict__ Dw,
    unsigned short* __restrict__ yg) {
  const int bi = blockIdx.x;           // 512 = 2b * 32h * 8pblk
  const int b = bi >> 8;
  const int h = (bi >> 3) & 31;
  const int pblk = bi & 7;
  const int tid = threadIdx.x;         // 64
  const int pl = tid & 7;
  const int p = pblk * 8 + pl;
  const int g = tid >> 3;              // 0..7 -> n = g*16 .. g*16+15
  const size_t tok0 = (size_t)b * T_SEQ;

  float s[16];
#pragma unroll
  for (int j = 0; j < 16; ++j) s[j] = 0.f;
  const float Dh = Dw[h];

  float Ba[16], Ca[16], Bb_[16], Cb_[16];
  unsigned short xa, za, xb, zb;
  float dta, daa, dtb_, dab;

  auto load = [&](int t, float (&Bv)[16], float (&Cv)[16], unsigned short& xv,
                  unsigned short& zv, float& dtv, float& dav) {
    size_t tk = tok0 + t;
    const float4* bp = (const float4*)(bcf + tk * 256 + g * 16);
    const float4* cp = (const float4*)(bcf + tk * 256 + 128 + g * 16);
#pragma unroll
    for (int q = 0; q < 4; ++q) {
      float4 bv = bp[q]; float4 cv = cp[q];
      Bv[q * 4 + 0] = bv.x; Bv[q * 4 + 1] = bv.y; Bv[q * 4 + 2] = bv.z; Bv[q * 4 + 3] = bv.w;
      Cv[q * 4 + 0] = cv.x; Cv[q * 4 + 1] = cv.y; Cv[q * 4 + 2] = cv.z; Cv[q * 4 + 3] = cv.w;
    }
    xv = xbc[tk * CONVCH + h * HEADDIM + p];
    zv = zx[tk * DINPROJ + h * HEADDIM + p];
    dtv = dtf[tk * NHEADS + h];
    dav = dAf[tk * NHEADS + h];
  };

  auto compute = [&](int t, const float (&Bv)[16], const float (&Cv)[16],
                     unsigned short xv, unsigned short zv, float dtv, float dav) {
    float xvf = b2f(xv);
    float coef = dtv * xvf;
    float acc = 0.f;
#pragma unroll
    for (int j = 0; j < 16; ++j) {
      s[j] = fmaf(dav, s[j], coef * Bv[j]);
      acc = fmaf(s[j], Cv[j], acc);
    }
    acc += __shfl_xor(acc, 8, 64);
    acc += __shfl_xor(acc, 16, 64);
    acc += __shfl_xor(acc, 32, 64);
    if (g == 0) {
      float zf = b2f(zv);
      float gate = zf / (1.f + expf(-zf));
      float yv = (acc + Dh * xvf) * gate;
      yg[(tok0 + t) * DINNER + h * HEADDIM + p] = f2b(yv);
    }
  };

  load(0, Ba, Ca, xa, za, dta, daa);
  for (int t = 0; t < T_SEQ; t += 2) {
    load(t + 1, Bb_, Cb_, xb, zb, dtb_, dab);
    compute(t, Ba, Ca, xa, za, dta, daa);
    if (t + 2 < T_SEQ) load(t + 2, Ba, Ca, xa, za, dta, daa);
    compute(t + 1, Bb_, Cb_, xb, zb, dtb_, dab);
  }
}

// ---------------- RMSNorm over 2048 (bf16 in/out, fp32 weight) ----------------
__global__ void rms2048_k(const unsigned short* __restrict__ in,
                          const float* __restrict__ w,
                          unsigned short* __restrict__ out) {
  int t = blockIdx.x;
  int base = threadIdx.x * 8;
  union { uint4 q; unsigned short u[8]; } vv;
  vv.q = *(const uint4*)(in + (size_t)t * DINNER + base);
  float f[8];
  float ss = 0.f;
#pragma unroll
  for (int j = 0; j < 8; ++j) { f[j] = b2f(vv.u[j]); ss += f[j] * f[j]; }
#pragma unroll
  for (int o = 32; o > 0; o >>= 1) ss += __shfl_xor(ss, o, 64);
  __shared__ float red[4];
  if ((threadIdx.x & 63) == 0) red[threadIdx.x >> 6] = ss;
  __syncthreads();
  ss = red[0] + red[1] + red[2] + red[3];
  float scale = rsqrtf(ss * (1.f / DINNER) + EPS_F);
#pragma unroll
  for (int j = 0; j < 8; ++j)
    out[(size_t)t * DINNER + base + j] = f2b(f[j] * scale * w[base + j]);
}

// ---------------- final RMSNorm over 1024 (fp32 in, fp32 weight, bf16 out) ----------------
__global__ void rmsfinal_k(const float* __restrict__ hf,
                           const float* __restrict__ w,
                           unsigned short* __restrict__ out) {
  int t = blockIdx.x;
  int base = threadIdx.x * 4;
  float4 v = *(const float4*)(hf + (size_t)t * DIM + base);
  float ss = v.x * v.x + v.y * v.y + v.z * v.z + v.w * v.w;
#pragma unroll
  for (int o = 32; o > 0; o >>= 1) ss += __shfl_xor(ss, o, 64);
  __shared__ float red[4];
  if ((threadIdx.x & 63) == 0) red[threadIdx.x >> 6] = ss;
  __syncthreads();
  ss = red[0] + red[1] + red[2] + red[3];
  float scale = rsqrtf(ss * (1.f / DIM) + EPS_F);
  out[(size_t)t * DIM + base + 0] = f2b(v.x * scale * w[base + 0]);
  out[(size_t)t * DIM + base + 1] = f2b(v.y * scale * w[base + 1]);
  out[(size_t)t * DIM + base + 2] = f2b(v.z * scale * w[base + 2]);
  out[(size_t)t * DIM + base + 3] = f2b(v.w * scale * w[base + 3]);
}

extern "C" void kernel_launch(void* const* d_in, const int* in_sizes, int n_in,
                              void* d_out, int out_size, void* d_ws, size_t ws_size,
                              hipStream_t stream) {
  const int*   x    = (const int*)d_in[0];
  const float* emb  = (const float*)d_in[1];
  const float* Wp   = (const float*)d_in[2];
  const float* cw   = (const float*)d_in[3];
  const float* cb   = (const float*)d_in[4];
  const float* dtb  = (const float*)d_in[5];
  const float* alog = (const float*)d_in[6];
  const float* Dw   = (const float*)d_in[7];
  const float* gw   = (const float*)d_in[8];
  const float* Wo   = (const float*)d_in[9];
  const float* fnw  = (const float*)d_in[10];

  char* w = (char*)d_ws;
  auto alloc = [&](size_t bytes) {
    char* p = w; w += (bytes + 255) & ~(size_t)255; return p;
  };
  float* h_f32          = (float*)alloc((size_t)BT * DIM * 4);
  unsigned short* hb    = (unsigned short*)alloc((size_t)BT * DIM * 2);
  unsigned short* zx    = (unsigned short*)alloc((size_t)BT * DINPROJ * 2);
  float* dtraw          = (float*)alloc((size_t)BT * NHEADS * 4);
  float* dtf            = (float*)alloc((size_t)BT * NHEADS * 4);
  float* dAf            = (float*)alloc((size_t)BT * NHEADS * 4);
  unsigned short* xbc   = (unsigned short*)alloc((size_t)BT * CONVCH * 2);
  float* bcf            = (float*)alloc((size_t)BT * 256 * 4);
  unsigned short* yg    = (unsigned short*)alloc((size_t)BT * DINNER * 2);
  unsigned short* yn    = (unsigned short*)alloc((size_t)BT * DINNER * 2);
  unsigned short* hn    = (unsigned short*)alloc((size_t)BT * DIM * 2);
  unsigned short* Wp_b  = (unsigned short*)alloc((size_t)2 * DINPROJ * DIM * 2);
  unsigned short* Wo_b  = (unsigned short*)alloc((size_t)2 * DIM * DINNER * 2);
  unsigned short* emb_b = (unsigned short*)alloc((size_t)256 * DIM * 2);

  // fp32 -> bf16 weight conversions
  {
    int nWp = 2 * DINPROJ * DIM;
    int nWo = 2 * DIM * DINNER;
    int nEm = 256 * DIM;
    cvt_k<<<(nWp / 4 + 255) / 256, 256, 0, stream>>>(Wp, Wp_b, nWp);
    cvt_k<<<(nWo / 4 + 255) / 256, 256, 0, stream>>>(Wo, Wo_b, nWo);
    cvt_k<<<(nEm / 4 + 255) / 256, 256, 0, stream>>>(emb, emb_b, nEm);
  }

  embed_k<<<BT, 256, 0, stream>>>(x, emb, h_f32, hb);

  for (int l = 0; l < 2; ++l) {
    const unsigned short* Wpl = Wp_b + (size_t)l * DINPROJ * DIM;
    const unsigned short* Wol = Wo_b + (size_t)l * DIM * DINNER;
    const float* cwl   = cw + (size_t)l * CONVCH * 4;
    const float* cbl   = cb + (size_t)l * CONVCH;
    const float* dtbl  = dtb + l * NHEADS;
    const float* alogl = alog + l * NHEADS;
    const float* Dwl   = Dw + l * NHEADS;
    const float* gwl   = gw + (size_t)l * DINNER;

    gemm_bt<0><<<dim3(35, 16), 256, 0, stream>>>(hb, Wpl, BT, DINPROJ, DIM, zx, dtraw, nullptr);
    conv_k<<<BT, 256, 0, stream>>>(zx, cwl, cbl, xbc, bcf);
    dt_k<<<BT * NHEADS / 256, 256, 0, stream>>>(dtraw, dtbl, alogl, dtf, dAf);
    scan_k<<<512, 64, 0, stream>>>(xbc, bcf, zx, dtf, dAf, Dwl, yg);
    rms2048_k<<<BT, 256, 0, stream>>>(yg, gwl, yn);
    gemm_bt<1><<<dim3(8, 16), 256, 0, stream>>>(yn, Wol, BT, DIM, DINNER, nullptr, h_f32, hb);
  }

  rmsfinal_k<<<BT, 256, 0, stream>>>(h_f32, fnw, hn);
  gemm_bt<2><<<dim3(2, 16), 256, 0, stream>>>(hn, emb_b, BT, 256, DIM,
                                              nullptr, (float*)d_out, nullptr);
}